// Round 8
// baseline (65.126 us; speedup 1.0000x reference)
//
#include <hip/hip_runtime.h>
#include <math.h>

// AEV computer (ANI-style): 32 molecules x 48 atoms, 4 species.
// Output: f32[32*48*384]; per atom 64 radial (s*16+t) + 320 angular (p*32+ia*8+iz).
// R8: no bucketing (cndmask scatter to 10 reg accumulators), register-resident
// setup with __shfl center broadcast, 4 barriers total.

#define A_ATOMS 48
#define NMOL    32
#define NFEAT   384
#define CHUNK   256

// cos/sin of SHFZ = (2*iz+1)*pi/16, iz = 0..7
__device__ __constant__ float CZ_TAB[8] = {
     0.980785280f,  0.831469612f,  0.555570233f,  0.195090322f,
    -0.195090322f, -0.555570233f, -0.831469612f, -0.980785280f };
__device__ __constant__ float SZ_TAB[8] = {
     0.195090322f,  0.555570233f,  0.831469612f,  0.980785280f,
     0.980785280f,  0.831469612f,  0.555570233f,  0.195090322f };

__device__ __forceinline__ float bf2f(unsigned short h) {
    return __uint_as_float(((unsigned int)h) << 16);
}

__global__ __launch_bounds__(256, 6)
void AEVComputer_2156073583107_kernel(const void* __restrict__ coords_raw,
                                      const void* __restrict__ species_raw,
                                      float* __restrict__ out)
{
    const int bid   = blockIdx.x;
    const int n     = bid / A_ATOMS;      // molecule
    const int i     = bid - n * A_ATOMS;  // center atom
    const int tid   = threadIdx.x;
    const int w     = tid >> 6;           // wave 0..3
    const int lane  = tid & 63;
    const int sub   = lane >> 5;
    const int slice = (w << 1) | sub;     // 0..7
    const int t     = lane & 31;          // feature t = ia*8+iz

    __shared__ float dL[A_ATOMS], fcaL[A_ATOMS];
    __shared__ float ux[A_ATOMS], uy[A_ATOMS], uz[A_ATOMS];
    __shared__ int   sp[A_ATOMS], nbr[A_ATOMS];
    __shared__ int   Msh;
    __shared__ float4 pairD[CHUNK];
    __shared__ int    pairP[CHUNK];
    __shared__ float  rad_m[4][64];
    __shared__ float  ang_m[8][320];

    const unsigned short* cu16 = (const unsigned short*)coords_raw;
    const unsigned int*   su32 = (const unsigned int*)species_raw;

    // ---- wave 0: sniff + load + geometry + neighbor list, register-resident ----
    if (tid < 64) {
        // dtype sniffs: one load + ballot each
        float v = bf2f(cu16[tid]);
        unsigned long long mb = __ballot(fabsf(v) < 32.0f);
        const bool coords_bf16 = (__popcll(mb) >= 60);   // f32 scores ~48, bf16 64
        unsigned int svv = su32[tid & 31];
        unsigned long long m2 = __ballot((tid < 32) && svv >= 0x3F000000u && svv < 0x40800000u);
        unsigned long long m3 = __ballot((tid < 32) && (tid & 1) && svv != 0u);
        const int smode = (__popcll(m2) > 20) ? 2 : ((m3 == 0ull) ? 1 : 0);

        float x = 0.f, y = 0.f, z = 0.f; int s = 0;
        if (tid < A_ATOMS) {
            const int g = n * A_ATOMS + tid;
            if (coords_bf16) {
                x = bf2f(cu16[3 * g]); y = bf2f(cu16[3 * g + 1]); z = bf2f(cu16[3 * g + 2]);
            } else {
                const float* cf = (const float*)coords_raw;
                x = cf[3 * g]; y = cf[3 * g + 1]; z = cf[3 * g + 2];
            }
            if (smode == 0)      s = ((const int*)species_raw)[g];
            else if (smode == 1) s = ((const int*)species_raw)[2 * g];
            else                 s = (int)(((const float*)species_raw)[g] + 0.5f);
            s = (s < 0) ? 0 : ((s > 3) ? 3 : s);
        }
        // center coords via in-register shuffle (i < 48 always)
        const float xi = __shfl(x, i), yi = __shfl(y, i), zi = __shfl(z, i);
        float dx = x - xi, dy = y - yi, dz = z - zi;
        float d2 = dx * dx + dy * dy + dz * dz;
        float d  = (tid == i) ? 1.0f : sqrtf(d2);
        float inv = 1.0f / d;
        bool pred = (tid < A_ATOMS) && (tid != i) && (d < 3.5f);
        float fca = pred ? (0.5f * __cosf(0.8975979010f * d) + 0.5f) : 0.0f;  // pi/3.5
        if (tid < A_ATOMS) {
            dL[tid] = d;
            ux[tid] = dx * inv; uy[tid] = dy * inv; uz[tid] = dz * inv;
            fcaL[tid] = fca; sp[tid] = s;
        }
        unsigned long long mask = __ballot(pred);
        if (pred) {
            int pos = __popcll(mask & ((1ull << tid) - 1ull));
            nbr[pos] = tid;
        }
        if (tid == 0) Msh = __popcll(mask);
    }
    __syncthreads();
    const int M = Msh;
    const int npairs = (M * (M - 1)) >> 1;

    // ---- radial: j strided over waves, fully unrolled, branchless ----
    {
        const int   s    = lane >> 4;
        const int   rt   = lane & 15;
        const float shfr = 0.9f + 0.26875f * (float)rt;
        float radv = 0.0f;
        #pragma unroll
        for (int jj = 0; jj < 12; ++jj) {
            const int j = w + 4 * jj;
            float d   = dL[j];
            float fcr = 0.5f * __cosf(0.6041524333f * d) + 0.5f;   // pi/5.2
            float e   = d - shfr;
            float val = 0.25f * __expf(-16.0f * e * e) * fcr;
            bool  ok  = (j != i) && (d < 5.2f) && (sp[j] == s);
            radv += ok ? val : 0.0f;
        }
        rad_m[w][lane] = radv;
    }

    // ---- angular ----
    float a[10];
    #pragma unroll
    for (int p = 0; p < 10; ++p) a[p] = 0.0f;
    const float czv  = CZ_TAB[t & 7];
    const float szv  = SZ_TAB[t & 7];
    const float shfa = 0.9f + 0.65f * (float)(t >> 3);

    for (int base = 0; base < npairs; base += CHUNK) {
        const int q = base + tid;
        if (q < npairs) {
            // decode triangular index q -> (jj,kk), jj<kk<M
            const float b = (float)(2 * M - 1);
            int jj = (int)(0.5f * (b - sqrtf(fmaxf(b * b - 8.0f * (float)q, 0.0f))));
            jj = max(0, min(jj, M - 2));
            while (jj > 0 && q < ((jj * (2 * M - 1 - jj)) >> 1)) --jj;
            while (q >= (((jj + 1) * (2 * M - 2 - jj)) >> 1)) ++jj;
            const int kk = jj + 1 + (q - ((jj * (2 * M - 1 - jj)) >> 1));
            const int j = nbr[jj], k = nbr[kk];
            float c  = fmaf(ux[j], ux[k], fmaf(uy[j], uy[k], uz[j] * uz[k]));
            float cc = 0.95f * c;
            float ss = sqrtf(fmaxf(1.0f - cc * cc, 0.0f));
            float4 pd;
            pd.x = 0.5f * cc;                    // hc
            pd.y = 0.5f * ss;                    // hs
            pd.z = 2.0f * fcaL[j] * fcaL[k];     // weight (x2: unordered pairs)
            pd.w = 0.5f * (dL[j] + dL[k]);       // dmean
            const int sj = sp[j], sk = sp[k];
            const int lo = min(sj, sk), hi = max(sj, sk);
            pairD[tid] = pd;
            pairP[tid] = ((lo * (7 - lo)) >> 1) + hi;   // TRIU pair index (verified)
        }
        __syncthreads();
        const int cnt = min(CHUNK, npairs - base);
        for (int qq = slice; qq < cnt; qq += 8) {
            float4 v = pairD[qq];                // broadcast (2 addrs/wave)
            int    p = pairP[qq];
            float x  = fmaf(v.y, szv, fmaf(v.x, czv, 0.5f));  // 0.5*(1+cos(th-z))
            float x2 = x * x, x4 = x2 * x2, x8 = x4 * x4, x16 = x8 * x8;
            float f1 = x16 * x16;                // x^32
            float e  = v.w - shfa;
            float term = v.z * __expf(-8.0f * e * e) * f1;
            #pragma unroll
            for (int pp = 0; pp < 10; ++pp) a[pp] += (p == pp) ? term : 0.0f;
        }
        __syncthreads();   // protect pairD/pairP before next chunk
    }

    #pragma unroll
    for (int pp = 0; pp < 10; ++pp) ang_m[slice][pp * 32 + t] = a[pp];
    __syncthreads();

    // ---- merge + store 384 f32 features ----
    const size_t outb = (size_t)bid * NFEAT;
    for (int f = tid; f < NFEAT; f += 256) {
        float v;
        if (f < 64) {
            v = rad_m[0][f] + rad_m[1][f] + rad_m[2][f] + rad_m[3][f];
        } else {
            const int g = f - 64;
            v = ((ang_m[0][g] + ang_m[1][g]) + (ang_m[2][g] + ang_m[3][g]))
              + ((ang_m[4][g] + ang_m[5][g]) + (ang_m[6][g] + ang_m[7][g]));
        }
        out[outb + f] = v;
    }
}

extern "C" void kernel_launch(void* const* d_in, const int* in_sizes, int n_in,
                              void* d_out, int out_size, void* d_ws, size_t ws_size,
                              hipStream_t stream) {
    if (n_in < 2) return;
    // Coordinates buffer has 3x the elements of species; pick by size so input
    // ORDER cannot break us.
    const void* coords;
    const void* species;
    if (in_sizes[0] >= in_sizes[1]) { coords = d_in[0]; species = d_in[1]; }
    else                            { coords = d_in[1]; species = d_in[0]; }
    float* out = (float*)d_out;
    AEVComputer_2156073583107_kernel<<<NMOL * A_ATOMS, 256, 0, stream>>>(coords, species, out);
}

// Round 9
// 63.929 us; speedup vs baseline: 1.0187x; 1.0187x over previous
//
#include <hip/hip_runtime.h>
#include <math.h>

// AEV computer (ANI-style): 32 molecules x 48 atoms, 4 species.
// Output: f32[32*48*384]; per atom 64 radial (s*16+t) + 320 angular (p*32+ia*8+iz).
// R9: phase A precomputes per-pair wf2[ia] (f2 factored out of phase B) and
// bucket-sorts pairs by species-pair p; phase B is uniform-p, 8 VALU + 2 LDS
// per pair-feature.

#define A_ATOMS 48
#define NMOL    32
#define NFEAT   384
#define CHUNK   256

// cos/sin of SHFZ = (2*iz+1)*pi/16, iz = 0..7
__device__ __constant__ float CZ_TAB[8] = {
     0.980785280f,  0.831469612f,  0.555570233f,  0.195090322f,
    -0.195090322f, -0.555570233f, -0.831469612f, -0.980785280f };
__device__ __constant__ float SZ_TAB[8] = {
     0.195090322f,  0.555570233f,  0.831469612f,  0.980785280f,
     0.980785280f,  0.831469612f,  0.555570233f,  0.195090322f };

__device__ __forceinline__ float bf2f(unsigned short h) {
    return __uint_as_float(((unsigned int)h) << 16);
}

__global__ __launch_bounds__(256, 6)
void AEVComputer_2156073583107_kernel(const void* __restrict__ coords_raw,
                                      const void* __restrict__ species_raw,
                                      float* __restrict__ out)
{
    const int bid   = blockIdx.x;
    const int n     = bid / A_ATOMS;      // molecule
    const int i     = bid - n * A_ATOMS;  // center atom
    const int tid   = threadIdx.x;
    const int w     = tid >> 6;           // wave 0..3
    const int lane  = tid & 63;
    const int sub   = lane >> 5;
    const int slice = (w << 1) | sub;     // 0..7
    const int t     = lane & 31;          // feature t = ia*8+iz
    const int ia    = t >> 3;

    __shared__ float dL[A_ATOMS], fcaL[A_ATOMS];
    __shared__ float ux[A_ATOMS], uy[A_ATOMS], uz[A_ATOMS];
    __shared__ int   sp[A_ATOMS], nbr[A_ATOMS];
    __shared__ int   Msh;
    __shared__ float2 pairA[CHUNK];       // (hc, hs)
    __shared__ float  pairW[CHUNK * 4];   // wf2[ia] = 2*fj*fk*exp(-8(dm-shfa)^2)
    __shared__ int   cnt[10], curs[10], ofs[11];
    __shared__ float rad_m[4][64];
    __shared__ float ang_m[8][320];

    const unsigned short* cu16 = (const unsigned short*)coords_raw;
    const unsigned int*   su32 = (const unsigned int*)species_raw;

    // ---- wave 0: sniff + load + geometry + neighbor list, register-resident ----
    if (tid < 64) {
        float v = bf2f(cu16[tid]);
        unsigned long long mb = __ballot(fabsf(v) < 32.0f);
        const bool coords_bf16 = (__popcll(mb) >= 60);   // f32 scores ~48, bf16 64
        unsigned int svv = su32[tid & 31];
        unsigned long long m2 = __ballot((tid < 32) && svv >= 0x3F000000u && svv < 0x40800000u);
        unsigned long long m3 = __ballot((tid < 32) && (tid & 1) && svv != 0u);
        const int smode = (__popcll(m2) > 20) ? 2 : ((m3 == 0ull) ? 1 : 0);

        float x = 0.f, y = 0.f, z = 0.f; int s = 0;
        if (tid < A_ATOMS) {
            const int g = n * A_ATOMS + tid;
            if (coords_bf16) {
                x = bf2f(cu16[3 * g]); y = bf2f(cu16[3 * g + 1]); z = bf2f(cu16[3 * g + 2]);
            } else {
                const float* cf = (const float*)coords_raw;
                x = cf[3 * g]; y = cf[3 * g + 1]; z = cf[3 * g + 2];
            }
            if (smode == 0)      s = ((const int*)species_raw)[g];
            else if (smode == 1) s = ((const int*)species_raw)[2 * g];
            else                 s = (int)(((const float*)species_raw)[g] + 0.5f);
            s = (s < 0) ? 0 : ((s > 3) ? 3 : s);
        }
        const float xi = __shfl(x, i), yi = __shfl(y, i), zi = __shfl(z, i);
        float dx = x - xi, dy = y - yi, dz = z - zi;
        float d2 = dx * dx + dy * dy + dz * dz;
        float d  = (tid == i) ? 1.0f : sqrtf(d2);
        float inv = 1.0f / d;
        bool pred = (tid < A_ATOMS) && (tid != i) && (d < 3.5f);
        float fca = pred ? (0.5f * __cosf(0.8975979010f * d) + 0.5f) : 0.0f;  // pi/3.5
        if (tid < A_ATOMS) {
            dL[tid] = d;
            ux[tid] = dx * inv; uy[tid] = dy * inv; uz[tid] = dz * inv;
            fcaL[tid] = fca; sp[tid] = s;
        }
        unsigned long long mask = __ballot(pred);
        if (pred) {
            int pos = __popcll(mask & ((1ull << tid) - 1ull));
            nbr[pos] = tid;
        }
        if (tid == 0) Msh = __popcll(mask);
    }
    __syncthreads();
    const int M = Msh;
    const int npairs = (M * (M - 1)) >> 1;

    // ---- radial: j strided over waves, fully unrolled, branchless ----
    {
        const int   s    = lane >> 4;
        const int   rt   = lane & 15;
        const float shfr = 0.9f + 0.26875f * (float)rt;
        float radv = 0.0f;
        #pragma unroll
        for (int jj = 0; jj < 12; ++jj) {
            const int j = w + 4 * jj;
            float d   = dL[j];
            float fcr = 0.5f * __cosf(0.6041524333f * d) + 0.5f;   // pi/5.2
            float e   = d - shfr;
            float val = 0.25f * __expf(-16.0f * e * e) * fcr;
            bool  ok  = (j != i) && (d < 5.2f) && (sp[j] == s);
            radv += ok ? val : 0.0f;
        }
        rad_m[w][lane] = radv;
    }

    // ---- angular ----
    float a[10];
    #pragma unroll
    for (int p = 0; p < 10; ++p) a[p] = 0.0f;
    const float czv = CZ_TAB[t & 7];
    const float szv = SZ_TAB[t & 7];

    for (int base = 0; base < npairs; base += CHUNK) {
        if (tid < 10) cnt[tid] = 0;
        __syncthreads();

        const int  q     = base + tid;
        const bool havep = (q < npairs);
        float2 pa; float wf[4]; int p = 0;
        if (havep) {
            // decode triangular index q -> (jj,kk), jj<kk<M
            const float b = (float)(2 * M - 1);
            int jj = (int)(0.5f * (b - sqrtf(fmaxf(b * b - 8.0f * (float)q, 0.0f))));
            jj = max(0, min(jj, M - 2));
            while (jj > 0 && q < ((jj * (2 * M - 1 - jj)) >> 1)) --jj;
            while (q >= (((jj + 1) * (2 * M - 2 - jj)) >> 1)) ++jj;
            const int kk = jj + 1 + (q - ((jj * (2 * M - 1 - jj)) >> 1));
            const int j = nbr[jj], k = nbr[kk];
            float c  = fmaf(ux[j], ux[k], fmaf(uy[j], uy[k], uz[j] * uz[k]));
            float cc = 0.95f * c;
            float ss = sqrtf(fmaxf(1.0f - cc * cc, 0.0f));
            pa.x = 0.5f * cc;                    // hc
            pa.y = 0.5f * ss;                    // hs
            const float wgt = 2.0f * fcaL[j] * fcaL[k];   // x2: unordered pairs
            const float dm  = 0.5f * (dL[j] + dL[k]);
            #pragma unroll
            for (int q4 = 0; q4 < 4; ++q4) {
                float e = dm - (0.9f + 0.65f * (float)q4);
                wf[q4] = wgt * __expf(-8.0f * e * e);
            }
            const int sj = sp[j], sk = sp[k];
            const int lo = min(sj, sk), hi = max(sj, sk);
            p = ((lo * (7 - lo)) >> 1) + hi;     // TRIU pair index (verified)
            atomicAdd(&cnt[p], 1);
        }
        __syncthreads();
        if (tid == 0) {
            int o = 0;
            #pragma unroll
            for (int pp = 0; pp < 10; ++pp) { ofs[pp] = o; curs[pp] = o; o += cnt[pp]; }
            ofs[10] = o;
        }
        __syncthreads();
        if (havep) {
            int slot = atomicAdd(&curs[p], 1);
            pairA[slot] = pa;
            pairW[4 * slot + 0] = wf[0];
            pairW[4 * slot + 1] = wf[1];
            pairW[4 * slot + 2] = wf[2];
            pairW[4 * slot + 3] = wf[3];
        }
        __syncthreads();

        // phase B: uniform-p buckets; 8 half-wave slices stride pairs.
        // Per iter: ds_read_b64 (broadcast) + ds_read_b32 + 8 VALU.
        #pragma unroll
        for (int pp = 0; pp < 10; ++pp) {
            const int e1 = ofs[pp + 1];
            float acc = a[pp];
            for (int qq = ofs[pp] + slice; qq < e1; qq += 8) {
                float2 v  = pairA[qq];
                float wf2 = pairW[4 * qq + ia];
                float x   = fmaf(v.y, szv, fmaf(v.x, czv, 0.5f));  // 0.5*(1+cos(th-z))
                float x2 = x * x, x4 = x2 * x2, x8 = x4 * x4, x16 = x8 * x8;
                acc = fmaf(x16 * x16, wf2, acc);                   // += wf2 * x^32
            }
            a[pp] = acc;
        }
        __syncthreads();   // protect pair buffers before next chunk
    }

    #pragma unroll
    for (int pp = 0; pp < 10; ++pp) ang_m[slice][pp * 32 + t] = a[pp];
    __syncthreads();

    // ---- merge + store 384 f32 features ----
    const size_t outb = (size_t)bid * NFEAT;
    for (int f = tid; f < NFEAT; f += 256) {
        float v;
        if (f < 64) {
            v = rad_m[0][f] + rad_m[1][f] + rad_m[2][f] + rad_m[3][f];
        } else {
            const int g = f - 64;
            v = ((ang_m[0][g] + ang_m[1][g]) + (ang_m[2][g] + ang_m[3][g]))
              + ((ang_m[4][g] + ang_m[5][g]) + (ang_m[6][g] + ang_m[7][g]));
        }
        out[outb + f] = v;
    }
}

extern "C" void kernel_launch(void* const* d_in, const int* in_sizes, int n_in,
                              void* d_out, int out_size, void* d_ws, size_t ws_size,
                              hipStream_t stream) {
    if (n_in < 2) return;
    // Coordinates buffer has 3x the elements of species; pick by size so input
    // ORDER cannot break us.
    const void* coords;
    const void* species;
    if (in_sizes[0] >= in_sizes[1]) { coords = d_in[0]; species = d_in[1]; }
    else                            { coords = d_in[1]; species = d_in[0]; }
    float* out = (float*)d_out;
    AEVComputer_2156073583107_kernel<<<NMOL * A_ATOMS, 256, 0, stream>>>(coords, species, out);
}

// Round 10
// 61.630 us; speedup vs baseline: 1.0567x; 1.0373x over previous
//
#include <hip/hip_runtime.h>
#include <math.h>

// AEV computer (ANI-style): 32 molecules x 48 atoms, 4 species.
// Output: f32[32*48*384]; per atom 64 radial (s*16+t) + 320 angular (p*32+ia*8+iz).
// R10: speculative dtype loads (no sniff->load chain), packed float4 geometry
// (radial = 1 b128 + 6 VALU/iter, fcr hoisted to setup), phase-B 2-way unroll
// with register bucket offsets, CHUNK=384 single-pass.

#define A_ATOMS 48
#define NMOL    32
#define NFEAT   384
#define CHUNK   384

// cos/sin of SHFZ = (2*iz+1)*pi/16, iz = 0..7
__device__ __constant__ float CZ_TAB[8] = {
     0.980785280f,  0.831469612f,  0.555570233f,  0.195090322f,
    -0.195090322f, -0.555570233f, -0.831469612f, -0.980785280f };
__device__ __constant__ float SZ_TAB[8] = {
     0.195090322f,  0.555570233f,  0.831469612f,  0.980785280f,
     0.980785280f,  0.831469612f,  0.555570233f,  0.195090322f };

__device__ __forceinline__ float bf2f(unsigned short h) {
    return __uint_as_float(((unsigned int)h) << 16);
}

__global__ __launch_bounds__(256, 6)
void AEVComputer_2156073583107_kernel(const void* __restrict__ coords_raw,
                                      const void* __restrict__ species_raw,
                                      float* __restrict__ out)
{
    const int bid   = blockIdx.x;
    const int n     = bid / A_ATOMS;      // molecule
    const int i     = bid - n * A_ATOMS;  // center atom
    const int tid   = threadIdx.x;
    const int w     = tid >> 6;           // wave 0..3
    const int lane  = tid & 63;
    const int sub   = lane >> 5;
    const int slice = (w << 1) | sub;     // 0..7
    const int t     = lane & 31;          // feature t = ia*8+iz
    const int ia    = t >> 3;

    __shared__ float4 geom[A_ATOMS];      // (d, rv=0.25*fcr*mask, fca, spf)
    __shared__ float4 uvec[A_ATOMS];      // (ux, uy, uz, spf)
    __shared__ int    nbr[A_ATOMS];
    __shared__ int    Msh;
    __shared__ float2 pairA[CHUNK];       // (hc, hs)
    __shared__ float  pairW[CHUNK * 4];   // wf2[ia]
    __shared__ int    cnt[10], curs[10], ofs[11];
    __shared__ float  rad_m[4][64];
    __shared__ float  ang_m[8][320];

    const unsigned short* cu16 = (const unsigned short*)coords_raw;
    const unsigned int*   su32 = (const unsigned int*)species_raw;

    // ---- wave 0: sniff + speculative loads + geometry + neighbor list ----
    if (tid < 64) {
        if (tid < 10) cnt[tid] = 0;       // pre-zero bucket counts (chunk 0)
        // speculative loads issued up-front (independent of sniff result)
        float xf = 0.f, yf = 0.f, zf = 0.f; unsigned int uraw = 0u;
        if (tid < A_ATOMS) {
            const int g = n * A_ATOMS + tid;
            const float* cf = (const float*)coords_raw;
            xf = cf[3 * g]; yf = cf[3 * g + 1]; zf = cf[3 * g + 2];
            uraw = su32[g];
        }
        // dtype sniffs: one load + ballot each
        float v = bf2f(cu16[tid]);
        unsigned long long mb = __ballot(fabsf(v) < 32.0f);
        const bool coords_bf16 = (__popcll(mb) >= 60);   // f32 scores ~48, bf16 64
        unsigned int svv = su32[tid & 31];
        unsigned long long m2 = __ballot((tid < 32) && svv >= 0x3F000000u && svv < 0x40800000u);
        unsigned long long m3 = __ballot((tid < 32) && (tid & 1) && svv != 0u);
        const int smode = (__popcll(m2) > 20) ? 2 : ((m3 == 0ull) ? 1 : 0);

        float x = xf, y = yf, z = zf; int s = 0;
        if (tid < A_ATOMS) {
            const int g = n * A_ATOMS + tid;
            if (coords_bf16) {            // rare path (harness delivers f32)
                x = bf2f(cu16[3 * g]); y = bf2f(cu16[3 * g + 1]); z = bf2f(cu16[3 * g + 2]);
            }
            if (smode == 1) uraw = su32[2 * g];           // rare path (i64)
            s = (smode == 2) ? (int)(__uint_as_float(uraw) + 0.5f) : (int)uraw;
            s = (s < 0) ? 0 : ((s > 3) ? 3 : s);
        }
        const float xi = __shfl(x, i), yi = __shfl(y, i), zi = __shfl(z, i);
        float dx = x - xi, dy = y - yi, dz = z - zi;
        float d2 = dx * dx + dy * dy + dz * dz;
        float d  = (tid == i) ? 1.0f : sqrtf(d2);
        float inv = 1.0f / d;
        bool  self = (tid >= A_ATOMS) || (tid == i);
        bool  predA = !self && (d < 3.5f);
        bool  predR = !self && (d < 5.2f);
        float fca = predA ? (0.5f * __cosf(0.8975979010f * d) + 0.5f) : 0.0f;  // pi/3.5
        float rv  = predR ? (0.25f * (0.5f * __cosf(0.6041524333f * d) + 0.5f)) : 0.0f; // 0.25*fcr
        if (tid < A_ATOMS) {
            float spf = (float)s;
            geom[tid] = make_float4(d, rv, fca, spf);
            uvec[tid] = make_float4(dx * inv, dy * inv, dz * inv, spf);
        }
        unsigned long long mask = __ballot(predA);
        if (predA) {
            int pos = __popcll(mask & ((1ull << tid) - 1ull));
            nbr[pos] = tid;
        }
        if (tid == 0) Msh = __popcll(mask);
    }
    __syncthreads();
    const int M = Msh;
    const int npairs = (M * (M - 1)) >> 1;

    // ---- radial: 1 broadcast b128 + ~6 VALU per iter, fully unrolled ----
    {
        const float sf   = (float)(lane >> 4);
        const float shfr = 0.9f + 0.26875f * (float)(lane & 15);
        float radv = 0.0f;
        #pragma unroll
        for (int jj = 0; jj < 12; ++jj) {
            const float4 gm = geom[w + 4 * jj];
            float e   = gm.x - shfr;
            float val = __expf(-16.0f * e * e) * gm.y;   // rv==0 masks self+cutoff
            radv += (gm.w == sf) ? val : 0.0f;
        }
        rad_m[w][lane] = radv;
    }

    // ---- angular ----
    float a[10];
    #pragma unroll
    for (int p = 0; p < 10; ++p) a[p] = 0.0f;
    const float czv = CZ_TAB[t & 7];
    const float szv = SZ_TAB[t & 7];

    for (int base = 0; base < npairs; base += CHUNK) {
        if (base > 0) {                   // re-zero counts for rare extra chunks
            if (tid < 10) cnt[tid] = 0;
            __syncthreads();
        }
        const int nch = min(CHUNK, npairs - base);

        // phase A: up to 2 pairs/thread (q0 = tid, q1 = tid + 256)
        float2 pa0, pa1; float wf0[4], wf1[4]; int p0 = 0, p1 = 0;
        const bool h0 = (tid < nch);
        const bool h1 = (tid + 256 < nch);
        #pragma unroll
        for (int pass = 0; pass < 2; ++pass) {
            const bool hv = pass ? h1 : h0;
            if (!hv) continue;
            const int q = base + tid + (pass ? 256 : 0);
            // decode triangular index q -> (jj,kk), jj<kk<M
            const float b = (float)(2 * M - 1);
            int jj = (int)(0.5f * (b - sqrtf(fmaxf(b * b - 8.0f * (float)q, 0.0f))));
            jj = max(0, min(jj, M - 2));
            while (jj > 0 && q < ((jj * (2 * M - 1 - jj)) >> 1)) --jj;
            while (q >= (((jj + 1) * (2 * M - 2 - jj)) >> 1)) ++jj;
            const int kk = jj + 1 + (q - ((jj * (2 * M - 1 - jj)) >> 1));
            const int j = nbr[jj], k = nbr[kk];
            const float4 gj = geom[j], gk = geom[k];
            const float4 uj = uvec[j], uk = uvec[k];
            float c  = fmaf(uj.x, uk.x, fmaf(uj.y, uk.y, uj.z * uk.z));
            float cc = 0.95f * c;
            float ss = sqrtf(fmaxf(1.0f - cc * cc, 0.0f));
            float2 pa = make_float2(0.5f * cc, 0.5f * ss);
            const float wgt = 2.0f * gj.z * gk.z;        // x2: unordered pairs
            const float dm  = 0.5f * (gj.x + gk.x);
            float wf[4];
            #pragma unroll
            for (int q4 = 0; q4 < 4; ++q4) {
                float e = dm - (0.9f + 0.65f * (float)q4);
                wf[q4] = wgt * __expf(-8.0f * e * e);
            }
            const int sj = (int)gj.w, sk = (int)gk.w;
            const int lo = min(sj, sk), hi = max(sj, sk);
            const int p = ((lo * (7 - lo)) >> 1) + hi;   // TRIU pair index (verified)
            atomicAdd(&cnt[p], 1);
            if (pass) { pa1 = pa; wf1[0]=wf[0]; wf1[1]=wf[1]; wf1[2]=wf[2]; wf1[3]=wf[3]; p1 = p; }
            else      { pa0 = pa; wf0[0]=wf[0]; wf0[1]=wf[1]; wf0[2]=wf[2]; wf0[3]=wf[3]; p0 = p; }
        }
        __syncthreads();
        if (tid == 0) {
            int o = 0;
            #pragma unroll
            for (int pp = 0; pp < 10; ++pp) { ofs[pp] = o; curs[pp] = o; o += cnt[pp]; }
            ofs[10] = o;
        }
        __syncthreads();
        if (h0) {
            int slot = atomicAdd(&curs[p0], 1);
            pairA[slot] = pa0;
            pairW[4*slot+0]=wf0[0]; pairW[4*slot+1]=wf0[1];
            pairW[4*slot+2]=wf0[2]; pairW[4*slot+3]=wf0[3];
        }
        if (h1) {
            int slot = atomicAdd(&curs[p1], 1);
            pairA[slot] = pa1;
            pairW[4*slot+0]=wf1[0]; pairW[4*slot+1]=wf1[1];
            pairW[4*slot+2]=wf1[2]; pairW[4*slot+3]=wf1[3];
        }
        __syncthreads();

        // bucket offsets -> registers
        int O[11];
        #pragma unroll
        for (int pp = 0; pp < 11; ++pp) O[pp] = ofs[pp];

        // phase B: uniform-p buckets, 2-way unrolled, 8 half-wave slices
        #pragma unroll
        for (int pp = 0; pp < 10; ++pp) {
            const int e1 = O[pp + 1];
            int qq = O[pp] + slice;
            float acc = a[pp];
            for (; qq + 8 < e1; qq += 16) {
                float2 v0  = pairA[qq];
                float  w0  = pairW[4 * qq + ia];
                float2 v1  = pairA[qq + 8];
                float  w1  = pairW[4 * (qq + 8) + ia];
                float x0 = fmaf(v0.y, szv, fmaf(v0.x, czv, 0.5f));
                float x1 = fmaf(v1.y, szv, fmaf(v1.x, czv, 0.5f));
                float a2 = x0*x0, b2 = x1*x1;
                float a4 = a2*a2, b4 = b2*b2;
                float a8 = a4*a4, b8 = b4*b4;
                float a16 = a8*a8, b16 = b8*b8;
                acc = fmaf(a16 * a16, w0, acc);
                acc = fmaf(b16 * b16, w1, acc);
            }
            if (qq < e1) {
                float2 v0 = pairA[qq];
                float  w0 = pairW[4 * qq + ia];
                float x0 = fmaf(v0.y, szv, fmaf(v0.x, czv, 0.5f));
                float a2 = x0*x0, a4 = a2*a2, a8 = a4*a4, a16 = a8*a8;
                acc = fmaf(a16 * a16, w0, acc);
            }
            a[pp] = acc;
        }
        if (base + CHUNK < npairs) __syncthreads();  // protect buffers (rare)
    }

    #pragma unroll
    for (int pp = 0; pp < 10; ++pp) ang_m[slice][pp * 32 + t] = a[pp];
    __syncthreads();

    // ---- merge + store 384 f32 features ----
    const size_t outb = (size_t)bid * NFEAT;
    for (int f = tid; f < NFEAT; f += 256) {
        float v;
        if (f < 64) {
            v = rad_m[0][f] + rad_m[1][f] + rad_m[2][f] + rad_m[3][f];
        } else {
            const int g = f - 64;
            v = ((ang_m[0][g] + ang_m[1][g]) + (ang_m[2][g] + ang_m[3][g]))
              + ((ang_m[4][g] + ang_m[5][g]) + (ang_m[6][g] + ang_m[7][g]));
        }
        out[outb + f] = v;
    }
}

extern "C" void kernel_launch(void* const* d_in, const int* in_sizes, int n_in,
                              void* d_out, int out_size, void* d_ws, size_t ws_size,
                              hipStream_t stream) {
    if (n_in < 2) return;
    // Coordinates buffer has 3x the elements of species; pick by size so input
    // ORDER cannot break us.
    const void* coords;
    const void* species;
    if (in_sizes[0] >= in_sizes[1]) { coords = d_in[0]; species = d_in[1]; }
    else                            { coords = d_in[1]; species = d_in[0]; }
    float* out = (float*)d_out;
    AEVComputer_2156073583107_kernel<<<NMOL * A_ATOMS, 256, 0, stream>>>(coords, species, out);
}